// Round 7
// baseline (1102.938 us; speedup 1.0000x reference)
//
#include <hip/hip_runtime.h>
#include <math.h>

#define N_NODES 100000
#define D 128
#define E_EDGES 600000
#define BN_EPS 1e-5f
#define RPS (N_NODES + 4)                 // padded rowptr stride (keeps int4 alignment per relation)
#define N4V (N_NODES / 4)                 // 25000 int4 elements
#define SCAN_BLOCKS ((N4V + 255) / 256)   // 98

typedef __attribute__((ext_vector_type(8))) __bf16 bf16x8;
typedef __attribute__((ext_vector_type(4))) __bf16 bf16x4;
typedef __attribute__((ext_vector_type(16))) float f32x16;

// A-tile swizzle: full 4-bit XOR -> 2-way-max bank aliasing on MFMA reads
__device__ __forceinline__ int qswz(int row, int q) { return q ^ (row & 15); }
// B-tile swizzle (4 chunks of 8 bf16 per col)
__device__ __forceinline__ int swz(int row, int c) { return c ^ ((row >> 1) & 3); }

// ---------------- degree histogram (all 3 relations, 4 edges/thread) ----------------
__global__ __launch_bounds__(256) void hist_kernel(
    const int* __restrict__ s0, const int* __restrict__ d0,
    const int* __restrict__ s1, const int* __restrict__ d1,
    const int* __restrict__ s2, const int* __restrict__ d2,
    int* __restrict__ outdeg, int* __restrict__ indeg)
{
    const int r = blockIdx.y;
    const int* src = (r == 0) ? s0 : ((r == 1) ? s1 : s2);
    const int* dst = (r == 0) ? d0 : ((r == 1) ? d1 : d2);
    int* od = outdeg + (size_t)r * N_NODES;
    int* id = indeg + (size_t)r * N_NODES;
    int i4 = blockIdx.x * 256 + threadIdx.x;
    if (i4 < E_EDGES / 4) {
        int4 s = ((const int4*)src)[i4];
        int4 d = ((const int4*)dst)[i4];
        atomicAdd(&od[s.x], 1); atomicAdd(&od[s.y], 1);
        atomicAdd(&od[s.z], 1); atomicAdd(&od[s.w], 1);
        atomicAdd(&id[d.x], 1); atomicAdd(&id[d.y], 1);
        atomicAdd(&id[d.z], 1); atomicAdd(&id[d.w], 1);
    }
}

// ---------------- norms ----------------
__global__ __launch_bounds__(256) void norm_kernel(
    const int* __restrict__ outdeg, const int* __restrict__ indeg,
    float* __restrict__ ns, float* __restrict__ nd)
{
    int n = blockIdx.x * 256 + threadIdx.x;
    int r = blockIdx.y;
    if (n < N_NODES) {
        int od = outdeg[r * N_NODES + n];
        int id = indeg[r * N_NODES + n];
        ns[r * N_NODES + n] = rsqrtf((float)(od < 1 ? 1 : od));
        nd[r * N_NODES + n] = rsqrtf((float)(id < 1 ? 1 : id));
    }
}

// ---------------- parallel scan, pass 1: per-block local exclusive scan ----------------
__global__ __launch_bounds__(256) void scan_part_kernel(
    const int* __restrict__ indeg, int* __restrict__ rowptr, int* __restrict__ bsum)
{
    const int r = blockIdx.y;
    const int t = threadIdx.x;
    const int lane = t & 63, wid = t >> 6;
    __shared__ int wsum[4], woff[4];
    int i4 = blockIdx.x * 256 + t;
    int4 v = (i4 < N4V) ? ((const int4*)(indeg + (size_t)r * N_NODES))[i4]
                        : make_int4(0, 0, 0, 0);
    int s0 = v.x, s1 = s0 + v.y, s2 = s1 + v.z, s3 = s2 + v.w;
    int x = s3;
    #pragma unroll
    for (int off = 1; off < 64; off <<= 1) {
        int y = __shfl_up(x, off);
        if (lane >= off) x += y;
    }
    if (lane == 63) wsum[wid] = x;
    __syncthreads();
    if (t < 4) { int s = 0; for (int j = 0; j < t; ++j) s += wsum[j]; woff[t] = s; }
    __syncthreads();
    int base = woff[wid] + (x - s3);
    if (i4 < N4V) {
        int idx = i4 * 4;
        int* rp = rowptr + (size_t)r * RPS;
        rp[idx] = base; rp[idx + 1] = base + s0; rp[idx + 2] = base + s1; rp[idx + 3] = base + s2;
    }
    if (t == 255) bsum[r * SCAN_BLOCKS + blockIdx.x] = woff[3] + wsum[3];
}

// ---------------- scan pass 2: scan the 98 block sums (per relation) ----------------
__global__ __launch_bounds__(256) void scan_mid_kernel(
    int* __restrict__ bsum, int* __restrict__ rowptr)
{
    const int t = threadIdx.x;
    const int lane = t & 63, wid = t >> 6;
    if (wid >= 3) return;
    const int r = wid;
    int carry = 0;
    for (int c = 0; c < (SCAN_BLOCKS + 63) / 64; ++c) {
        int idx = c * 64 + lane;
        int v = (idx < SCAN_BLOCKS) ? bsum[r * SCAN_BLOCKS + idx] : 0;
        int x = v;
        #pragma unroll
        for (int off = 1; off < 64; off <<= 1) {
            int y = __shfl_up(x, off);
            if (lane >= off) x += y;
        }
        if (idx < SCAN_BLOCKS) bsum[r * SCAN_BLOCKS + idx] = carry + x - v;
        carry += __shfl(x, 63);
    }
    if (lane == 0) rowptr[(size_t)r * RPS + N_NODES] = carry;
}

// ---------------- scan pass 3: add block offsets, emit cursor copy ----------------
__global__ __launch_bounds__(256) void scan_add_kernel(
    int* __restrict__ rowptr, const int* __restrict__ bsum, int* __restrict__ cursor)
{
    const int r = blockIdx.y;
    int i4 = blockIdx.x * 256 + threadIdx.x;
    if (i4 < N4V) {
        int off = bsum[r * SCAN_BLOCKS + blockIdx.x];
        int4* rp4 = (int4*)(rowptr + (size_t)r * RPS);
        int4 v = rp4[i4];
        v.x += off; v.y += off; v.z += off; v.w += off;
        rp4[i4] = v;
        ((int4*)(cursor + (size_t)r * N_NODES))[i4] = v;
    }
}

// ---------------- CSR fill: edge record {src, ns[src]} ----------------
__global__ __launch_bounds__(256) void fill_kernel(
    const int* __restrict__ s0, const int* __restrict__ d0,
    const int* __restrict__ s1, const int* __restrict__ d1,
    const int* __restrict__ s2, const int* __restrict__ d2,
    const float* __restrict__ nsv,
    int* __restrict__ cursor, int2* __restrict__ eint)
{
    const int r = blockIdx.y;
    const int* src = (r == 0) ? s0 : ((r == 1) ? s1 : s2);
    const int* dst = (r == 0) ? d0 : ((r == 1) ? d1 : d2);
    int* cur = cursor + (size_t)r * N_NODES;
    int2* eg = eint + (size_t)r * E_EDGES;
    const float* ns_ = nsv + (size_t)r * N_NODES;
    int i = blockIdx.x * 256 + threadIdx.x;
    if (i < E_EDGES) {
        int s = src[i];
        int d = dst[i];
        int pos = atomicAdd(&cur[d], 1);
        eg[pos] = make_int2(s, __float_as_int(ns_[s]));
    }
}

// ---------------- W' precompute: Wp[l,r] = Wrel[l,r] @ Wfc[l], BN-scaled, hi/lo, [col][k] ----------------
__global__ __launch_bounds__(256) void wprep_kernel(
    const float* __restrict__ Wrel, const float* __restrict__ Wfc,
    const float* __restrict__ gma, const float* __restrict__ rvar,
    __bf16* __restrict__ Whi, __bf16* __restrict__ Wlo)
{
    __shared__ float W1[128][132];
    __shared__ float W2[128][132];
    const int b = blockIdx.x;   // l*3+r
    const int l = b / 3;
    const int t = threadIdx.x;

    const float* src1 = Wrel + (size_t)b * D * D;
    const float* src2 = Wfc + (size_t)l * D * D;
    #pragma unroll
    for (int p = 0; p < 16; ++p) {
        int u = t + p * 256;
        int r = u >> 5, f = u & 31;
        float4 v1 = *(const float4*)(src1 + r * D + f * 4);
        float4 v2 = *(const float4*)(src2 + r * D + f * 4);
        *(float4*)&W1[r][f * 4] = v1;
        *(float4*)&W2[r][f * 4] = v2;
    }
    __syncthreads();

    const int row = t >> 1;
    const int cb = (t & 1) * 64;
    float4 acc4[16];
    #pragma unroll
    for (int j = 0; j < 16; ++j) acc4[j] = make_float4(0.f, 0.f, 0.f, 0.f);
    for (int k = 0; k < 128; ++k) {
        float a = W1[row][k];
        #pragma unroll
        for (int j = 0; j < 16; ++j) {
            float4 w = *(const float4*)&W2[k][cb + j * 4];
            acc4[j].x = fmaf(a, w.x, acc4[j].x);
            acc4[j].y = fmaf(a, w.y, acc4[j].y);
            acc4[j].z = fmaf(a, w.z, acc4[j].z);
            acc4[j].w = fmaf(a, w.w, acc4[j].w);
        }
    }
    for (int j = 0; j < 64; ++j) {
        int colj = cb + j;
        float s = 1.0f;
        if (l < 2) s = gma[l * D + colj] * rsqrtf(rvar[l * D + colj] + BN_EPS);
        float v = (&acc4[j >> 2].x)[j & 3] * s;
        __bf16 h = (__bf16)v;
        __bf16 lo = (__bf16)(v - (float)h);
        Whi[((size_t)b * D + colj) * D + row] = h;
        Wlo[((size_t)b * D + colj) * D + row] = lo;
    }
}

// ---------------- bias precompute ----------------
__global__ __launch_bounds__(128) void bias_prep_kernel(
    const float* __restrict__ brel, const float* __restrict__ Wfc,
    const float* __restrict__ bfc,
    const float* __restrict__ gma, const float* __restrict__ bta,
    const float* __restrict__ rmean, const float* __restrict__ rvar,
    float* __restrict__ bvec)
{
    int j = threadIdx.x;
    int l = blockIdx.x;
    float acc = bfc[l * D + j];
    for (int k = 0; k < D; ++k) {
        float bs = brel[(l * 3 + 0) * D + k] + brel[(l * 3 + 1) * D + k] + brel[(l * 3 + 2) * D + k];
        acc = fmaf(bs, Wfc[((size_t)l * D + k) * D + j], acc);
    }
    if (l < 2) {
        float s = gma[l * D + j] * rsqrtf(rvar[l * D + j] + BN_EPS);
        acc = acc * s + (bta[l * D + j] - rmean[l * D + j] * s);
    }
    bvec[l * D + j] = acc;
}

// NOTE: parameter names must not collide with float4 member names (.x/.y/.z/.w)
#define FMA8(W_, U_, V_)                                                       \
    acc0.x = fmaf(W_, U_.x, acc0.x); acc0.y = fmaf(W_, U_.y, acc0.y);          \
    acc0.z = fmaf(W_, U_.z, acc0.z); acc0.w = fmaf(W_, U_.w, acc0.w);          \
    acc1.x = fmaf(W_, V_.x, acc1.x); acc1.y = fmaf(W_, V_.y, acc1.y);          \
    acc1.z = fmaf(W_, V_.z, acc1.z); acc1.w = fmaf(W_, V_.w, acc1.w);

// ---------------- fused layer: gather -> bf16 hi/lo LDS -> MFMA vs W' (3 relations) ----------------
// BM=128 rows/block, 1024 threads = 16 waves (2 blocks/CU = 32 waves = 100% cap).
// wave w: rows (w&3)*32..+31, cols (w>>2)*32..+31. Gather: 16-lane groups, 2 rows each, 4-edge unroll.
__global__ __launch_bounds__(1024, 8) void fused_layer_kernel(
    const float* __restrict__ h,
    const int* __restrict__ rowptr,   // [3][RPS]
    const int2* __restrict__ eint,    // [3][E] {src, ns[src]}
    const float* __restrict__ ndv,    // [3][N]
    const __bf16* __restrict__ Whi,   // [3][col][k], this layer
    const __bf16* __restrict__ Wlo,
    float* __restrict__ out, const float* __restrict__ bias, int relu)
{
    __shared__ __bf16 Ah[128 * 128];   // 32 KB
    __shared__ __bf16 Al[128 * 128];   // 32 KB
    __shared__ __bf16 Bh[128 * 32];    // 8 KB
    __shared__ __bf16 Bl[128 * 32];    // 8 KB

    const int t = threadIdx.x;
    const int lane = t & 63;
    const int wid = t >> 6;           // 0..15
    const int wrow = wid & 3;         // 32-row quarter
    const int wcol = wid >> 2;        // 32-col quarter
    const int row0 = blockIdx.x * 128;
    const int g = t >> 4;             // 64 gather groups
    const int gl = t & 15;            // lane in group: k-cols gl*8..+7

    f32x16 acc;
    #pragma unroll
    for (int i = 0; i < 16; ++i) acc[i] = 0.0f;

    auto stageB = [&](int r_, int ks_) {
        int half = t & 1;
        int u = t >> 1;               // 0..511
        int colj = u >> 2;            // 0..127
        int c = u & 3;
        const __bf16* srcp = (half ? Wlo : Whi) + (size_t)r_ * D * D + (size_t)colj * D + ks_ * 32 + c * 8;
        __bf16* dstp = (half ? Bl : Bh) + colj * 32 + swz(colj, c) * 8;
        *(bf16x8*)dstp = *(const bf16x8*)srcp;
    };

    for (int r = 0; r < 3; ++r) {
        const int* rp = rowptr + (size_t)r * RPS;
        const int2* eg = eint + (size_t)r * E_EDGES;
        const float* nd_ = ndv + (size_t)r * N_NODES;

        stageB(r, 0);   // hidden under gather; covered by the barrier below

        // ---- gather: each 16-lane group accumulates 2 rows, 4-edge unroll ----
        #pragma unroll
        for (int rr = 0; rr < 2; ++rr) {
            int rowl = g * 2 + rr;
            int grow = row0 + rowl;
            float4 acc0 = {0, 0, 0, 0}, acc1 = {0, 0, 0, 0};
            if (grow < N_NODES) {
                int beg = rp[grow], end = rp[grow + 1];
                float sc = nd_[grow];
                int e = beg;
                for (; e + 4 <= end; e += 4) {
                    int2 r0 = eg[e], r1 = eg[e + 1], r2 = eg[e + 2], r3 = eg[e + 3];
                    const float* p0 = h + (size_t)r0.x * D + gl * 8;
                    const float* p1 = h + (size_t)r1.x * D + gl * 8;
                    const float* p2 = h + (size_t)r2.x * D + gl * 8;
                    const float* p3 = h + (size_t)r3.x * D + gl * 8;
                    float4 u0 = *(const float4*)p0, v0 = *(const float4*)(p0 + 4);
                    float4 u1 = *(const float4*)p1, v1 = *(const float4*)(p1 + 4);
                    float4 u2 = *(const float4*)p2, v2 = *(const float4*)(p2 + 4);
                    float4 u3 = *(const float4*)p3, v3 = *(const float4*)(p3 + 4);
                    float w0 = __int_as_float(r0.y), w1 = __int_as_float(r1.y);
                    float w2 = __int_as_float(r2.y), w3 = __int_as_float(r3.y);
                    FMA8(w0, u0, v0); FMA8(w1, u1, v1);
                    FMA8(w2, u2, v2); FMA8(w3, u3, v3);
                }
                if (e + 2 <= end) {
                    int2 r0 = eg[e], r1 = eg[e + 1];
                    const float* p0 = h + (size_t)r0.x * D + gl * 8;
                    const float* p1 = h + (size_t)r1.x * D + gl * 8;
                    float4 u0 = *(const float4*)p0, v0 = *(const float4*)(p0 + 4);
                    float4 u1 = *(const float4*)p1, v1 = *(const float4*)(p1 + 4);
                    float w0 = __int_as_float(r0.y), w1 = __int_as_float(r1.y);
                    FMA8(w0, u0, v0); FMA8(w1, u1, v1);
                    e += 2;
                }
                if (e < end) {
                    int2 r0 = eg[e];
                    const float* p0 = h + (size_t)r0.x * D + gl * 8;
                    float4 u0 = *(const float4*)p0, v0 = *(const float4*)(p0 + 4);
                    float w0 = __int_as_float(r0.y);
                    FMA8(w0, u0, v0);
                }
                acc0.x *= sc; acc0.y *= sc; acc0.z *= sc; acc0.w *= sc;
                acc1.x *= sc; acc1.y *= sc; acc1.z *= sc; acc1.w *= sc;
            }
            // convert hi/lo and write chunk q = gl (k = gl*8..+7)
            float a[8] = {acc0.x, acc0.y, acc0.z, acc0.w, acc1.x, acc1.y, acc1.z, acc1.w};
            bf16x8 hv, lv;
            #pragma unroll
            for (int c = 0; c < 8; ++c) {
                __bf16 hb = (__bf16)a[c];
                hv[c] = hb;
                lv[c] = (__bf16)(a[c] - (float)hb);
            }
            int idxA = rowl * 128 + qswz(rowl, gl) * 8;
            *(bf16x8*)&Ah[idxA] = hv;
            *(bf16x8*)&Al[idxA] = lv;
        }

        // ---- MFMA over 4 K-slices ----
        for (int ks = 0; ks < 4; ++ks) {
            __syncthreads();   // A+B(ks) writes visible
            const int arow = lane & 31;
            const int kgrp = lane >> 5;
            #pragma unroll
            for (int ksub = 0; ksub < 2; ++ksub) {
                int ac = ksub * 2 + kgrp;
                int arow_g = wrow * 32 + arow;
                int aidx = arow_g * 128 + qswz(arow_g, ks * 4 + ac) * 8;
                bf16x8 ahv = *(const bf16x8*)&Ah[aidx];
                bf16x8 alv = *(const bf16x8*)&Al[aidx];
                int colg = wcol * 32 + arow;
                int bidx = colg * 32 + swz(colg, ac) * 8;
                bf16x8 bhv = *(const bf16x8*)&Bh[bidx];
                bf16x8 blv = *(const bf16x8*)&Bl[bidx];
                acc = __builtin_amdgcn_mfma_f32_32x32x16_bf16(ahv, bhv, acc, 0, 0, 0);
                acc = __builtin_amdgcn_mfma_f32_32x32x16_bf16(ahv, blv, acc, 0, 0, 0);
                acc = __builtin_amdgcn_mfma_f32_32x32x16_bf16(alv, bhv, acc, 0, 0, 0);
            }
            __syncthreads();   // MFMA reads done before next stage/gather writes
            if (ks < 3) stageB(r, ks + 1);
        }
    }

    // ---- epilogue: bias (+ ReLU), nontemporal single write ----
    const int colb = lane & 31;
    const int rq = lane >> 5;
    {
        int colg = wcol * 32 + colb;
        float bv = bias[colg];
        #pragma unroll
        for (int reg = 0; reg < 16; ++reg) {
            int rowl = wrow * 32 + (reg & 3) + 8 * (reg >> 2) + 4 * rq;
            int grow = row0 + rowl;
            if (grow < N_NODES) {
                float z = acc[reg] + bv;
                if (relu) z = fmaxf(z, 0.f);
                __builtin_nontemporal_store(z, &out[(size_t)grow * D + colg]);
            }
        }
    }
}

// ---------------- launch ----------------
extern "C" void kernel_launch(void* const* d_in, const int* in_sizes, int n_in,
                              void* d_out, int out_size, void* d_ws, size_t ws_size,
                              hipStream_t stream)
{
    const float* x      = (const float*)d_in[0];
    const int* seq_src  = (const int*)d_in[1];
    const int* seq_dst  = (const int*)d_in[2];
    const int* knn_src  = (const int*)d_in[3];
    const int* knn_dst  = (const int*)d_in[4];
    const int* dis_src  = (const int*)d_in[5];
    const int* dis_dst  = (const int*)d_in[6];
    const float* Wrel   = (const float*)d_in[7];   // [3][3][128][128]
    const float* brel   = (const float*)d_in[8];   // [3][3][128]
    const float* Wfc    = (const float*)d_in[9];   // [3][128][128]
    const float* bfc    = (const float*)d_in[10];  // [3][128]
    const float* gma    = (const float*)d_in[11];  // [2][128]
    const float* bta    = (const float*)d_in[12];
    const float* rmean  = (const float*)d_in[13];
    const float* rvar   = (const float*)d_in[14];
    float* out = (float*)d_out;

    const size_t ND = (size_t)N_NODES * D;
    float* ws   = (float*)d_ws;
    float* h0   = ws;                         // N*D
    float* h1   = h0 + ND;                    // N*D
    float* ns_  = h1 + ND;                    // 3*N
    float* nd_  = ns_ + 3 * N_NODES;          // 3*N
    float* bvec = nd_ + 3 * N_NODES;          // 3*128
    __bf16* Whi = (__bf16*)(bvec + 3 * D);    // 9*128*128
    __bf16* Wlo = Whi + (size_t)9 * D * D;
    int* outdeg = (int*)(Wlo + (size_t)9 * D * D);   // 3*N
    int* indeg  = outdeg + 3 * N_NODES;               // 3*N
    int* rowptr = indeg + 3 * N_NODES;                // 3*RPS
    int* cursor = rowptr + 3 * RPS;                   // 3*N
    int* bsum   = cursor + 3 * N_NODES;               // 3*SCAN_BLOCKS
    int2* eint  = (int2*)(bsum + 3 * SCAN_BLOCKS + 2); // 3*E {src, w} (8B aligned)

    // ---- graph preprocessing ----
    hipMemsetAsync(outdeg, 0, (size_t)6 * N_NODES * sizeof(int), stream);
    hist_kernel<<<dim3((E_EDGES / 4 + 255) / 256, 3), 256, 0, stream>>>(
        seq_src, seq_dst, knn_src, knn_dst, dis_src, dis_dst, outdeg, indeg);
    norm_kernel<<<dim3((N_NODES + 255) / 256, 3), 256, 0, stream>>>(outdeg, indeg, ns_, nd_);
    scan_part_kernel<<<dim3(SCAN_BLOCKS, 3), 256, 0, stream>>>(indeg, rowptr, bsum);
    scan_mid_kernel<<<1, 256, 0, stream>>>(bsum, rowptr);
    scan_add_kernel<<<dim3(SCAN_BLOCKS, 3), 256, 0, stream>>>(rowptr, bsum, cursor);
    fill_kernel<<<dim3((E_EDGES + 255) / 256, 3), 256, 0, stream>>>(
        seq_src, seq_dst, knn_src, knn_dst, dis_src, dis_dst, ns_, cursor, eint);

    // ---- weight/bias precompute ----
    wprep_kernel<<<9, 256, 0, stream>>>(Wrel, Wfc, gma, rvar, Whi, Wlo);
    bias_prep_kernel<<<3, 128, 0, stream>>>(brel, Wfc, bfc, gma, bta, rmean, rvar, bvec);

    // ---- layers (fully fused) ----
    const int GB = (N_NODES + 127) / 128;   // 782
    fused_layer_kernel<<<GB, 1024, 0, stream>>>(
        x, rowptr, eint, nd_, Whi, Wlo, h0, bvec, 1);
    fused_layer_kernel<<<GB, 1024, 0, stream>>>(
        h0, rowptr, eint, nd_, Whi + (size_t)3 * D * D, Wlo + (size_t)3 * D * D,
        h1, bvec + D, 1);
    fused_layer_kernel<<<GB, 1024, 0, stream>>>(
        h1, rowptr, eint, nd_, Whi + (size_t)6 * D * D, Wlo + (size_t)6 * D * D,
        out, bvec + 2 * D, 0);
}

// Round 8
// 975.526 us; speedup vs baseline: 1.1306x; 1.1306x over previous
//
#include <hip/hip_runtime.h>
#include <math.h>

#define N_NODES 100000
#define D 128
#define E_EDGES 600000
#define BN_EPS 1e-5f

typedef __attribute__((ext_vector_type(8))) __bf16 bf16x8;
typedef __attribute__((ext_vector_type(4))) __bf16 bf16x4;
typedef __attribute__((ext_vector_type(16))) float f32x16;

#define BSTRIDE 40   // B-tile col stride in bf16 (80B -> 8 distinct bank offsets)

// A-tile swizzle: full 4-bit XOR -> <=2-way bank aliasing on MFMA reads
__device__ __forceinline__ int qswz(int row, int q) { return q ^ (row & 15); }
// B-tile chunk swizzle
__device__ __forceinline__ int swz(int row, int c) { return c ^ ((row >> 1) & 3); }

// ---------------- degree histogram (all 3 relations, 4 edges/thread) ----------------
__global__ __launch_bounds__(256) void hist_kernel(
    const int* __restrict__ s0, const int* __restrict__ d0,
    const int* __restrict__ s1, const int* __restrict__ d1,
    const int* __restrict__ s2, const int* __restrict__ d2,
    int* __restrict__ outdeg, int* __restrict__ indeg)
{
    const int r = blockIdx.y;
    const int* src = (r == 0) ? s0 : ((r == 1) ? s1 : s2);
    const int* dst = (r == 0) ? d0 : ((r == 1) ? d1 : d2);
    int* od = outdeg + (size_t)r * N_NODES;
    int* id = indeg + (size_t)r * N_NODES;
    int i4 = blockIdx.x * 256 + threadIdx.x;
    if (i4 < E_EDGES / 4) {
        int4 s = ((const int4*)src)[i4];
        int4 d = ((const int4*)dst)[i4];
        atomicAdd(&od[s.x], 1); atomicAdd(&od[s.y], 1);
        atomicAdd(&od[s.z], 1); atomicAdd(&od[s.w], 1);
        atomicAdd(&id[d.x], 1); atomicAdd(&id[d.y], 1);
        atomicAdd(&id[d.z], 1); atomicAdd(&id[d.w], 1);
    }
}

// ---------------- norms ----------------
__global__ __launch_bounds__(256) void norm_kernel(
    const int* __restrict__ outdeg, const int* __restrict__ indeg,
    float* __restrict__ ns, float* __restrict__ nd)
{
    int n = blockIdx.x * 256 + threadIdx.x;
    int r = blockIdx.y;
    if (n < N_NODES) {
        int od = outdeg[r * N_NODES + n];
        int id = indeg[r * N_NODES + n];
        ns[r * N_NODES + n] = rsqrtf((float)(od < 1 ? 1 : od));
        nd[r * N_NODES + n] = rsqrtf((float)(id < 1 ? 1 : id));
    }
}

// ---------------- exclusive scan of in-degrees -> CSR row_ptr (+cursor copy) ----------------
__global__ __launch_bounds__(1024) void scan_kernel(
    const int* __restrict__ indeg, int* __restrict__ rowptr, int* __restrict__ cursor)
{
    const int r = blockIdx.x;
    const int4* deg4 = (const int4*)(indeg + (size_t)r * N_NODES);
    int* rp = rowptr + (size_t)r * (N_NODES + 1);
    int* cur = cursor + (size_t)r * N_NODES;

    __shared__ int wsum[16];
    __shared__ int woff[16];
    __shared__ int chunk_total;

    const int tid = threadIdx.x;
    const int lane = tid & 63;
    const int wid = tid >> 6;
    const int N4 = N_NODES / 4;

    int running = 0;
    for (int base4 = 0; base4 < N4; base4 += 1024) {
        int i4 = base4 + tid;
        int4 v = (i4 < N4) ? deg4[i4] : make_int4(0, 0, 0, 0);
        int s0 = v.x, s1 = s0 + v.y, s2 = s1 + v.z, s3 = s2 + v.w;

        int x = s3;
        #pragma unroll
        for (int off = 1; off < 64; off <<= 1) {
            int y = __shfl_up(x, off);
            if (lane >= off) x += y;
        }
        if (lane == 63) wsum[wid] = x;
        __syncthreads();
        if (wid == 0) {
            int t = (lane < 16) ? wsum[lane] : 0;
            int xx = t;
            #pragma unroll
            for (int off = 1; off < 16; off <<= 1) {
                int y = __shfl_up(xx, off);
                if (lane >= off) xx += y;
            }
            if (lane < 16) woff[lane] = xx - t;
            if (lane == 15) chunk_total = xx;
        }
        __syncthreads();

        int texcl = x - s3;
        int offset = running + woff[wid] + texcl;
        if (i4 < N4) {
            int idx = i4 * 4;
            rp[idx]     = offset;       cur[idx]     = offset;
            rp[idx + 1] = offset + s0;  cur[idx + 1] = offset + s0;
            rp[idx + 2] = offset + s1;  cur[idx + 2] = offset + s1;
            rp[idx + 3] = offset + s2;  cur[idx + 3] = offset + s2;
        }
        running += chunk_total;
    }
    if (tid == 0) rp[N_NODES] = running;
}

// ---------------- CSR fill: edge record {src, ns[src]} ----------------
__global__ __launch_bounds__(256) void fill_kernel(
    const int* __restrict__ s0, const int* __restrict__ d0,
    const int* __restrict__ s1, const int* __restrict__ d1,
    const int* __restrict__ s2, const int* __restrict__ d2,
    const float* __restrict__ nsv,
    int* __restrict__ cursor, int2* __restrict__ eint)
{
    const int r = blockIdx.y;
    const int* src = (r == 0) ? s0 : ((r == 1) ? s1 : s2);
    const int* dst = (r == 0) ? d0 : ((r == 1) ? d1 : d2);
    int* cur = cursor + (size_t)r * N_NODES;
    int2* eg = eint + (size_t)r * E_EDGES;
    const float* ns_ = nsv + (size_t)r * N_NODES;
    int i = blockIdx.x * 256 + threadIdx.x;
    if (i < E_EDGES) {
        int s = src[i];
        int d = dst[i];
        int pos = atomicAdd(&cur[d], 1);
        eg[pos] = make_int2(s, __float_as_int(ns_[s]));
    }
}

// ---------------- W' precompute: Wp[l,r] = Wrel[l,r] @ Wfc[l], BN-scaled, hi/lo, [col][k] ----------------
__global__ __launch_bounds__(256) void wprep_kernel(
    const float* __restrict__ Wrel, const float* __restrict__ Wfc,
    const float* __restrict__ gma, const float* __restrict__ rvar,
    __bf16* __restrict__ Whi, __bf16* __restrict__ Wlo)
{
    __shared__ float W1[128][132];
    __shared__ float W2[128][132];
    const int b = blockIdx.x;   // l*3+r
    const int l = b / 3;
    const int t = threadIdx.x;

    const float* src1 = Wrel + (size_t)b * D * D;
    const float* src2 = Wfc + (size_t)l * D * D;
    #pragma unroll
    for (int p = 0; p < 16; ++p) {
        int u = t + p * 256;
        int r = u >> 5, f = u & 31;
        float4 v1 = *(const float4*)(src1 + r * D + f * 4);
        float4 v2 = *(const float4*)(src2 + r * D + f * 4);
        *(float4*)&W1[r][f * 4] = v1;
        *(float4*)&W2[r][f * 4] = v2;
    }
    __syncthreads();

    const int row = t >> 1;
    const int cb = (t & 1) * 64;
    float4 acc4[16];
    #pragma unroll
    for (int j = 0; j < 16; ++j) acc4[j] = make_float4(0.f, 0.f, 0.f, 0.f);
    for (int k = 0; k < 128; ++k) {
        float a = W1[row][k];
        #pragma unroll
        for (int j = 0; j < 16; ++j) {
            float4 w = *(const float4*)&W2[k][cb + j * 4];
            acc4[j].x = fmaf(a, w.x, acc4[j].x);
            acc4[j].y = fmaf(a, w.y, acc4[j].y);
            acc4[j].z = fmaf(a, w.z, acc4[j].z);
            acc4[j].w = fmaf(a, w.w, acc4[j].w);
        }
    }
    for (int j = 0; j < 64; ++j) {
        int colj = cb + j;
        float s = 1.0f;
        if (l < 2) s = gma[l * D + colj] * rsqrtf(rvar[l * D + colj] + BN_EPS);
        float v = (&acc4[j >> 2].x)[j & 3] * s;
        __bf16 h = (__bf16)v;
        __bf16 lo = (__bf16)(v - (float)h);
        Whi[((size_t)b * D + colj) * D + row] = h;
        Wlo[((size_t)b * D + colj) * D + row] = lo;
    }
}

// ---------------- bias precompute ----------------
__global__ __launch_bounds__(128) void bias_prep_kernel(
    const float* __restrict__ brel, const float* __restrict__ Wfc,
    const float* __restrict__ bfc,
    const float* __restrict__ gma, const float* __restrict__ bta,
    const float* __restrict__ rmean, const float* __restrict__ rvar,
    float* __restrict__ bvec)
{
    int j = threadIdx.x;
    int l = blockIdx.x;
    float acc = bfc[l * D + j];
    for (int k = 0; k < D; ++k) {
        float bs = brel[(l * 3 + 0) * D + k] + brel[(l * 3 + 1) * D + k] + brel[(l * 3 + 2) * D + k];
        acc = fmaf(bs, Wfc[((size_t)l * D + k) * D + j], acc);
    }
    if (l < 2) {
        float s = gma[l * D + j] * rsqrtf(rvar[l * D + j] + BN_EPS);
        acc = acc * s + (bta[l * D + j] - rmean[l * D + j] * s);
    }
    bvec[l * D + j] = acc;
}

// NOTE: macro parameter names must not collide with float4 member names
#define FMA8(W_, U_, V_)                                                       \
    acc0.x = fmaf(W_, U_.x, acc0.x); acc0.y = fmaf(W_, U_.y, acc0.y);          \
    acc0.z = fmaf(W_, U_.z, acc0.z); acc0.w = fmaf(W_, U_.w, acc0.w);          \
    acc1.x = fmaf(W_, V_.x, acc1.x); acc1.y = fmaf(W_, V_.y, acc1.y);          \
    acc1.z = fmaf(W_, V_.z, acc1.z); acc1.w = fmaf(W_, V_.w, acc1.w);

// ---------------- fused layer: gather -> bf16 hi/lo LDS -> MFMA vs W' (3 relations) ----------------
// BM=64 rows/block, 512 threads = 8 waves; wave w: rows (w&1)*32..+31, cols (w>>1)*32..+31
// LDS 52 KB -> 3 blocks/CU (24 waves/CU cap). Gather: 16-lane groups, 2 rows each, 4-edge unroll
// (2 float4/lane/edge -> 8 loads in flight at ~60 VGPR; launch_bounds(512,6) budget 85).
__global__ __launch_bounds__(512, 6) void fused_layer_kernel(
    const float* __restrict__ h,
    const int* __restrict__ rowptr,   // [3][N+1]
    const int2* __restrict__ eint,    // [3][E] {src, ns[src]}
    const float* __restrict__ ndv,    // [3][N]
    const __bf16* __restrict__ Whi,   // [3][col][k], this layer
    const __bf16* __restrict__ Wlo,
    float* __restrict__ out, const float* __restrict__ bias, int relu)
{
    __shared__ __bf16 Ah[64 * 128];          // 16 KB
    __shared__ __bf16 Al[64 * 128];          // 16 KB
    __shared__ __bf16 Bh[128 * BSTRIDE];     // 10 KB
    __shared__ __bf16 Bl[128 * BSTRIDE];     // 10 KB

    const int t = threadIdx.x;
    const int lane = t & 63;
    const int wid = t >> 6;           // 0..7
    const int wrow = wid & 1;         // 32-row half
    const int wcol = wid >> 1;        // 32-col quarter
    const int row0 = blockIdx.x * 64;
    const int g = t >> 4;             // 32 gather groups
    const int gl = t & 15;            // lane in group: k-cols gl*8..+7

    f32x16 acc;
    #pragma unroll
    for (int i = 0; i < 16; ++i) acc[i] = 0.0f;

    for (int r = 0; r < 3; ++r) {
        const int* rp = rowptr + (size_t)r * (N_NODES + 1);
        const int2* eg = eint + (size_t)r * E_EDGES;
        const float* nd_ = ndv + (size_t)r * N_NODES;

        // ---- gather: each 16-lane group accumulates 2 rows, 4-edge unroll ----
        #pragma unroll
        for (int rr = 0; rr < 2; ++rr) {
            int rowl = g * 2 + rr;
            int grow = row0 + rowl;
            float4 acc0 = {0, 0, 0, 0}, acc1 = {0, 0, 0, 0};
            if (grow < N_NODES) {
                int beg = rp[grow], end = rp[grow + 1];
                float sc = nd_[grow];
                int e = beg;
                for (; e + 4 <= end; e += 4) {
                    int2 r0 = eg[e], r1 = eg[e + 1], r2 = eg[e + 2], r3 = eg[e + 3];
                    const float* p0 = h + (size_t)r0.x * D + gl * 8;
                    const float* p1 = h + (size_t)r1.x * D + gl * 8;
                    const float* p2 = h + (size_t)r2.x * D + gl * 8;
                    const float* p3 = h + (size_t)r3.x * D + gl * 8;
                    float4 u0 = *(const float4*)p0, v0 = *(const float4*)(p0 + 4);
                    float4 u1 = *(const float4*)p1, v1 = *(const float4*)(p1 + 4);
                    float4 u2 = *(const float4*)p2, v2 = *(const float4*)(p2 + 4);
                    float4 u3 = *(const float4*)p3, v3 = *(const float4*)(p3 + 4);
                    float w0 = __int_as_float(r0.y), w1 = __int_as_float(r1.y);
                    float w2 = __int_as_float(r2.y), w3 = __int_as_float(r3.y);
                    FMA8(w0, u0, v0); FMA8(w1, u1, v1);
                    FMA8(w2, u2, v2); FMA8(w3, u3, v3);
                }
                if (e + 2 <= end) {
                    int2 r0 = eg[e], r1 = eg[e + 1];
                    const float* p0 = h + (size_t)r0.x * D + gl * 8;
                    const float* p1 = h + (size_t)r1.x * D + gl * 8;
                    float4 u0 = *(const float4*)p0, v0 = *(const float4*)(p0 + 4);
                    float4 u1 = *(const float4*)p1, v1 = *(const float4*)(p1 + 4);
                    float w0 = __int_as_float(r0.y), w1 = __int_as_float(r1.y);
                    FMA8(w0, u0, v0); FMA8(w1, u1, v1);
                    e += 2;
                }
                if (e < end) {
                    int2 r0 = eg[e];
                    const float* p0 = h + (size_t)r0.x * D + gl * 8;
                    float4 u0 = *(const float4*)p0, v0 = *(const float4*)(p0 + 4);
                    float w0 = __int_as_float(r0.y);
                    FMA8(w0, u0, v0);
                }
                acc0.x *= sc; acc0.y *= sc; acc0.z *= sc; acc0.w *= sc;
                acc1.x *= sc; acc1.y *= sc; acc1.z *= sc; acc1.w *= sc;
            }
            // convert hi/lo; lane covers chunk q = gl (k = gl*8..+7)
            float a[8] = {acc0.x, acc0.y, acc0.z, acc0.w, acc1.x, acc1.y, acc1.z, acc1.w};
            bf16x8 hv, lv;
            #pragma unroll
            for (int c = 0; c < 8; ++c) {
                __bf16 hb = (__bf16)a[c];
                hv[c] = hb;
                lv[c] = (__bf16)(a[c] - (float)hb);
            }
            int idxA = rowl * 128 + qswz(rowl, gl) * 8;
            *(bf16x8*)&Ah[idxA] = hv;
            *(bf16x8*)&Al[idxA] = lv;
        }

        // ---- MFMA over 4 K-slices ----
        for (int ks = 0; ks < 4; ++ks) {
            // stage B slice: 128 cols x 32 k (hi+lo per thread)
            {
                int colj = t >> 2;
                int c = t & 3;
                int idx = colj * BSTRIDE + swz(colj, c) * 8;
                const __bf16* sh = Whi + (size_t)r * D * D + (size_t)colj * D + ks * 32 + c * 8;
                const __bf16* sl = Wlo + (size_t)r * D * D + (size_t)colj * D + ks * 32 + c * 8;
                *(bf16x8*)&Bh[idx] = *(const bf16x8*)sh;
                *(bf16x8*)&Bl[idx] = *(const bf16x8*)sl;
            }
            __syncthreads();   // A-writes (ks==0) and B-writes visible

            const int arow = lane & 31;
            const int kgrp = lane >> 5;
            #pragma unroll
            for (int ksub = 0; ksub < 2; ++ksub) {
                int ac = ksub * 2 + kgrp;
                int arow_g = wrow * 32 + arow;
                int aidx = arow_g * 128 + qswz(arow_g, ks * 4 + ac) * 8;
                bf16x8 ahv = *(const bf16x8*)&Ah[aidx];
                bf16x8 alv = *(const bf16x8*)&Al[aidx];
                int colg = wcol * 32 + arow;
                int bidx = colg * BSTRIDE + swz(colg, ac) * 8;
                bf16x8 bhv = *(const bf16x8*)&Bh[bidx];
                bf16x8 blv = *(const bf16x8*)&Bl[bidx];
                acc = __builtin_amdgcn_mfma_f32_32x32x16_bf16(ahv, bhv, acc, 0, 0, 0);
                acc = __builtin_amdgcn_mfma_f32_32x32x16_bf16(ahv, blv, acc, 0, 0, 0);
                acc = __builtin_amdgcn_mfma_f32_32x32x16_bf16(alv, bhv, acc, 0, 0, 0);
            }
            __syncthreads();   // MFMA reads done before next stage/gather writes
        }
    }

    // ---- epilogue: bias (+ ReLU), single write ----
    const int colb = lane & 31;
    const int rq = lane >> 5;
    {
        int colg = wcol * 32 + colb;
        float bv = bias[colg];
        #pragma unroll
        for (int reg = 0; reg < 16; ++reg) {
            int rowl = wrow * 32 + (reg & 3) + 8 * (reg >> 2) + 4 * rq;
            int grow = row0 + rowl;
            if (grow < N_NODES) {
                float z = acc[reg] + bv;
                if (relu) z = fmaxf(z, 0.f);
                out[(size_t)grow * D + colg] = z;
            }
        }
    }
}

// ---------------- launch ----------------
extern "C" void kernel_launch(void* const* d_in, const int* in_sizes, int n_in,
                              void* d_out, int out_size, void* d_ws, size_t ws_size,
                              hipStream_t stream)
{
    const float* x      = (const float*)d_in[0];
    const int* seq_src  = (const int*)d_in[1];
    const int* seq_dst  = (const int*)d_in[2];
    const int* knn_src  = (const int*)d_in[3];
    const int* knn_dst  = (const int*)d_in[4];
    const int* dis_src  = (const int*)d_in[5];
    const int* dis_dst  = (const int*)d_in[6];
    const float* Wrel   = (const float*)d_in[7];   // [3][3][128][128]
    const float* brel   = (const float*)d_in[8];   // [3][3][128]
    const float* Wfc    = (const float*)d_in[9];   // [3][128][128]
    const float* bfc    = (const float*)d_in[10];  // [3][128]
    const float* gma    = (const float*)d_in[11];  // [2][128]
    const float* bta    = (const float*)d_in[12];
    const float* rmean  = (const float*)d_in[13];
    const float* rvar   = (const float*)d_in[14];
    float* out = (float*)d_out;

    const size_t ND = (size_t)N_NODES * D;
    float* ws   = (float*)d_ws;
    float* h0   = ws;                         // N*D
    float* h1   = h0 + ND;                    // N*D
    float* ns_  = h1 + ND;                    // 3*N
    float* nd_  = ns_ + 3 * N_NODES;          // 3*N
    float* bvec = nd_ + 3 * N_NODES;          // 3*128
    __bf16* Whi = (__bf16*)(bvec + 3 * D);    // 9*128*128
    __bf16* Wlo = Whi + (size_t)9 * D * D;
    int* outdeg = (int*)(Wlo + (size_t)9 * D * D);   // 3*N
    int* indeg  = outdeg + 3 * N_NODES;               // 3*N
    int* rowptr = indeg + 3 * N_NODES;                // 3*(N+1) (+1 pad for alignment)
    int* cursor = rowptr + 3 * (N_NODES + 1) + 1;     // 3*N
    int2* eint  = (int2*)(cursor + 3 * N_NODES);      // 3*E {src, w}

    const int* srcs[3] = {seq_src, knn_src, dis_src};
    const int* dsts[3] = {seq_dst, knn_dst, dis_dst};
    (void)srcs; (void)dsts;

    // ---- graph preprocessing ----
    hipMemsetAsync(outdeg, 0, (size_t)6 * N_NODES * sizeof(int), stream);
    hist_kernel<<<dim3((E_EDGES / 4 + 255) / 256, 3), 256, 0, stream>>>(
        seq_src, seq_dst, knn_src, knn_dst, dis_src, dis_dst, outdeg, indeg);
    norm_kernel<<<dim3((N_NODES + 255) / 256, 3), 256, 0, stream>>>(outdeg, indeg, ns_, nd_);
    scan_kernel<<<3, 1024, 0, stream>>>(indeg, rowptr, cursor);
    fill_kernel<<<dim3((E_EDGES + 255) / 256, 3), 256, 0, stream>>>(
        seq_src, seq_dst, knn_src, knn_dst, dis_src, dis_dst, ns_, cursor, eint);

    // ---- weight/bias precompute ----
    wprep_kernel<<<9, 256, 0, stream>>>(Wrel, Wfc, gma, rvar, Whi, Wlo);
    bias_prep_kernel<<<3, 128, 0, stream>>>(brel, Wfc, bfc, gma, bta, rmean, rvar, bvec);

    // ---- layers (fully fused) ----
    const int GB = (N_NODES + 63) / 64;   // 1563
    fused_layer_kernel<<<GB, 512, 0, stream>>>(
        x, rowptr, eint, nd_, Whi, Wlo, h0, bvec, 1);
    fused_layer_kernel<<<GB, 512, 0, stream>>>(
        h0, rowptr, eint, nd_, Whi + (size_t)3 * D * D, Wlo + (size_t)3 * D * D,
        h1, bvec + D, 1);
    fused_layer_kernel<<<GB, 512, 0, stream>>>(
        h1, rowptr, eint, nd_, Whi + (size_t)6 * D * D, Wlo + (size_t)6 * D * D,
        out, bvec + 2 * D, 0);
}

// Round 9
// 791.674 us; speedup vs baseline: 1.3932x; 1.2322x over previous
//
#include <hip/hip_runtime.h>
#include <math.h>

#define N_NODES 100000
#define D 128
#define E_EDGES 600000
#define BN_EPS 1e-5f
#define RPS (N_NODES + 4)                 // padded rowptr stride per relation
#define N4V (N_NODES / 4)                 // 25000 int4 elements
#define SCAN_BLOCKS ((N4V + 255) / 256)   // 98

typedef __attribute__((ext_vector_type(8))) __bf16 bf16x8;
typedef __attribute__((ext_vector_type(4))) __bf16 bf16x4;
typedef __attribute__((ext_vector_type(16))) float f32x16;

// A-tile swizzle: full 4-bit XOR (best measured: 3.6M conflicts at BM=128)
__device__ __forceinline__ int qswz(int row, int q) { return q ^ (row & 15); }
// B-tile chunk swizzle
__device__ __forceinline__ int swz(int row, int c) { return c ^ ((row >> 1) & 3); }

// ---------------- degree histogram (all 3 relations, 4 edges/thread) ----------------
__global__ __launch_bounds__(256) void hist_kernel(
    const int* __restrict__ s0, const int* __restrict__ d0,
    const int* __restrict__ s1, const int* __restrict__ d1,
    const int* __restrict__ s2, const int* __restrict__ d2,
    int* __restrict__ outdeg, int* __restrict__ indeg)
{
    const int r = blockIdx.y;
    const int* src = (r == 0) ? s0 : ((r == 1) ? s1 : s2);
    const int* dst = (r == 0) ? d0 : ((r == 1) ? d1 : d2);
    int* od = outdeg + (size_t)r * N_NODES;
    int* id = indeg + (size_t)r * N_NODES;
    int i4 = blockIdx.x * 256 + threadIdx.x;
    if (i4 < E_EDGES / 4) {
        int4 s = ((const int4*)src)[i4];
        int4 d = ((const int4*)dst)[i4];
        atomicAdd(&od[s.x], 1); atomicAdd(&od[s.y], 1);
        atomicAdd(&od[s.z], 1); atomicAdd(&od[s.w], 1);
        atomicAdd(&id[d.x], 1); atomicAdd(&id[d.y], 1);
        atomicAdd(&id[d.z], 1); atomicAdd(&id[d.w], 1);
    }
}

// ---------------- norms ----------------
__global__ __launch_bounds__(256) void norm_kernel(
    const int* __restrict__ outdeg, const int* __restrict__ indeg,
    float* __restrict__ ns, float* __restrict__ nd)
{
    int n = blockIdx.x * 256 + threadIdx.x;
    int r = blockIdx.y;
    if (n < N_NODES) {
        int od = outdeg[r * N_NODES + n];
        int id = indeg[r * N_NODES + n];
        ns[r * N_NODES + n] = rsqrtf((float)(od < 1 ? 1 : od));
        nd[r * N_NODES + n] = rsqrtf((float)(id < 1 ? 1 : id));
    }
}

// ---------------- parallel scan pass 1: per-block local exclusive scan ----------------
__global__ __launch_bounds__(256) void scan_part_kernel(
    const int* __restrict__ indeg, int* __restrict__ rowptr, int* __restrict__ bsum)
{
    const int r = blockIdx.y;
    const int t = threadIdx.x;
    const int lane = t & 63, wid = t >> 6;
    __shared__ int wsum[4], woff[4];
    int i4 = blockIdx.x * 256 + t;
    int4 v = (i4 < N4V) ? ((const int4*)(indeg + (size_t)r * N_NODES))[i4]
                        : make_int4(0, 0, 0, 0);
    int s0 = v.x, s1 = s0 + v.y, s2 = s1 + v.z, s3 = s2 + v.w;
    int x = s3;
    #pragma unroll
    for (int off = 1; off < 64; off <<= 1) {
        int y = __shfl_up(x, off);
        if (lane >= off) x += y;
    }
    if (lane == 63) wsum[wid] = x;
    __syncthreads();
    if (t < 4) { int s = 0; for (int j = 0; j < t; ++j) s += wsum[j]; woff[t] = s; }
    __syncthreads();
    int base = woff[wid] + (x - s3);
    if (i4 < N4V) {
        int idx = i4 * 4;
        int* rp = rowptr + (size_t)r * RPS;
        rp[idx] = base; rp[idx + 1] = base + s0; rp[idx + 2] = base + s1; rp[idx + 3] = base + s2;
    }
    if (t == 255) bsum[r * SCAN_BLOCKS + blockIdx.x] = woff[3] + wsum[3];
}

// ---------------- scan pass 2 ----------------
__global__ __launch_bounds__(256) void scan_mid_kernel(
    int* __restrict__ bsum, int* __restrict__ rowptr)
{
    const int t = threadIdx.x;
    const int lane = t & 63, wid = t >> 6;
    if (wid >= 3) return;
    const int r = wid;
    int carry = 0;
    for (int c = 0; c < (SCAN_BLOCKS + 63) / 64; ++c) {
        int idx = c * 64 + lane;
        int v = (idx < SCAN_BLOCKS) ? bsum[r * SCAN_BLOCKS + idx] : 0;
        int x = v;
        #pragma unroll
        for (int off = 1; off < 64; off <<= 1) {
            int y = __shfl_up(x, off);
            if (lane >= off) x += y;
        }
        if (idx < SCAN_BLOCKS) bsum[r * SCAN_BLOCKS + idx] = carry + x - v;
        carry += __shfl(x, 63);
    }
    if (lane == 0) rowptr[(size_t)r * RPS + N_NODES] = carry;
}

// ---------------- scan pass 3: add block offsets, emit cursor copy ----------------
__global__ __launch_bounds__(256) void scan_add_kernel(
    int* __restrict__ rowptr, const int* __restrict__ bsum, int* __restrict__ cursor)
{
    const int r = blockIdx.y;
    int i4 = blockIdx.x * 256 + threadIdx.x;
    if (i4 < N4V) {
        int off = bsum[r * SCAN_BLOCKS + blockIdx.x];
        int4* rp4 = (int4*)(rowptr + (size_t)r * RPS);
        int4 v = rp4[i4];
        v.x += off; v.y += off; v.z += off; v.w += off;
        rp4[i4] = v;
        ((int4*)(cursor + (size_t)r * N_NODES))[i4] = v;
    }
}

// ---------------- CSR fill: edge record {src, ns[src]} ----------------
__global__ __launch_bounds__(256) void fill_kernel(
    const int* __restrict__ s0, const int* __restrict__ d0,
    const int* __restrict__ s1, const int* __restrict__ d1,
    const int* __restrict__ s2, const int* __restrict__ d2,
    const float* __restrict__ nsv,
    int* __restrict__ cursor, int2* __restrict__ eint)
{
    const int r = blockIdx.y;
    const int* src = (r == 0) ? s0 : ((r == 1) ? s1 : s2);
    const int* dst = (r == 0) ? d0 : ((r == 1) ? d1 : d2);
    int* cur = cursor + (size_t)r * N_NODES;
    int2* eg = eint + (size_t)r * E_EDGES;
    const float* ns_ = nsv + (size_t)r * N_NODES;
    int i = blockIdx.x * 256 + threadIdx.x;
    if (i < E_EDGES) {
        int s = src[i];
        int d = dst[i];
        int pos = atomicAdd(&cur[d], 1);
        eg[pos] = make_int2(s, __float_as_int(ns_[s]));
    }
}

// ---------------- W' precompute: grid (9, 8); block computes 16 k-rows x 128 cols ----------------
__global__ __launch_bounds__(256) void wprep_kernel(
    const float* __restrict__ Wrel, const float* __restrict__ Wfc,
    const float* __restrict__ gma, const float* __restrict__ rvar,
    __bf16* __restrict__ Whi, __bf16* __restrict__ Wlo)
{
    __shared__ float W2[128][132];
    __shared__ float W1p[16][132];
    const int b = blockIdx.x;   // l*3+r
    const int l = b / 3;
    const int by = blockIdx.y;  // k-row chunk
    const int t = threadIdx.x;

    const float* src1 = Wrel + (size_t)b * D * D;   // [k][j]
    const float* src2 = Wfc + (size_t)l * D * D;
    #pragma unroll
    for (int p = 0; p < 16; ++p) {
        int u = t + p * 256;
        int r = u >> 5, f = u & 31;
        *(float4*)&W2[r][f * 4] = *(const float4*)(src2 + r * D + f * 4);
    }
    #pragma unroll
    for (int p = 0; p < 2; ++p) {
        int u = t + p * 256;
        int r = u >> 5, f = u & 31;
        *(float4*)&W1p[r][f * 4] = *(const float4*)(src1 + (size_t)(by * 16 + r) * D + f * 4);
    }
    __syncthreads();

    const int rl = t >> 4;          // 0..15 local k-row
    const int cb = (t & 15) * 8;    // 8 cols
    float acc[8];
    #pragma unroll
    for (int j = 0; j < 8; ++j) acc[j] = 0.f;
    for (int k = 0; k < 128; ++k) {
        float a = W1p[rl][k];
        #pragma unroll
        for (int j = 0; j < 8; ++j) acc[j] = fmaf(a, W2[k][cb + j], acc[j]);
    }
    const int row = by * 16 + rl;
    #pragma unroll
    for (int j = 0; j < 8; ++j) {
        int colj = cb + j;
        float s = 1.0f;
        if (l < 2) s = gma[l * D + colj] * rsqrtf(rvar[l * D + colj] + BN_EPS);
        float v = acc[j] * s;
        __bf16 hb = (__bf16)v;
        __bf16 lb = (__bf16)(v - (float)hb);
        Whi[((size_t)b * D + colj) * D + row] = hb;
        Wlo[((size_t)b * D + colj) * D + row] = lb;
    }
}

// ---------------- bias precompute ----------------
__global__ __launch_bounds__(128) void bias_prep_kernel(
    const float* __restrict__ brel, const float* __restrict__ Wfc,
    const float* __restrict__ bfc,
    const float* __restrict__ gma, const float* __restrict__ bta,
    const float* __restrict__ rmean, const float* __restrict__ rvar,
    float* __restrict__ bvec)
{
    int j = threadIdx.x;
    int l = blockIdx.x;
    float acc = bfc[l * D + j];
    for (int k = 0; k < D; ++k) {
        float bs = brel[(l * 3 + 0) * D + k] + brel[(l * 3 + 1) * D + k] + brel[(l * 3 + 2) * D + k];
        acc = fmaf(bs, Wfc[((size_t)l * D + k) * D + j], acc);
    }
    if (l < 2) {
        float s = gma[l * D + j] * rsqrtf(rvar[l * D + j] + BN_EPS);
        acc = acc * s + (bta[l * D + j] - rmean[l * D + j] * s);
    }
    bvec[l * D + j] = acc;
}

// 16 FMAs of one edge's 4 float4 into the row accumulators a0..a3
#define FMA16(W_, P_, Q_, R_, S_)                                              \
    a0.x = fmaf(W_, P_.x, a0.x); a0.y = fmaf(W_, P_.y, a0.y);                  \
    a0.z = fmaf(W_, P_.z, a0.z); a0.w = fmaf(W_, P_.w, a0.w);                  \
    a1.x = fmaf(W_, Q_.x, a1.x); a1.y = fmaf(W_, Q_.y, a1.y);                  \
    a1.z = fmaf(W_, Q_.z, a1.z); a1.w = fmaf(W_, Q_.w, a1.w);                  \
    a2.x = fmaf(W_, R_.x, a2.x); a2.y = fmaf(W_, R_.y, a2.y);                  \
    a2.z = fmaf(W_, R_.z, a2.z); a2.w = fmaf(W_, R_.w, a2.w);                  \
    a3.x = fmaf(W_, S_.x, a3.x); a3.y = fmaf(W_, S_.y, a3.y);                  \
    a3.z = fmaf(W_, S_.z, a3.z); a3.w = fmaf(W_, S_.w, a3.w);

// ---------------- fused layer: gather -> bf16 hi/lo LDS -> MFMA vs W' (3 relations) ----------------
// BM=128 rows/block, 512 threads = 8 waves; wave w: rows (w&3)*32..+31, cols (w>>2)*64..+63.
// LDS 80 KB -> 2 blocks/CU. Gather: 8-lane groups, 2 rows each, 4-edge unroll
// (4 float4/lane/edge -> 16 loads in flight; launch_bounds(512,4) = 128 VGPR budget).
__global__ __launch_bounds__(512, 4) void fused_layer_kernel(
    const float* __restrict__ h,
    const int* __restrict__ rowptr,   // [3][RPS]
    const int2* __restrict__ eint,    // [3][E] {src, ns[src]}
    const float* __restrict__ ndv,    // [3][N]
    const __bf16* __restrict__ Whi,   // [3][col][k], this layer
    const __bf16* __restrict__ Wlo,
    float* __restrict__ out, const float* __restrict__ bias, int relu)
{
    __shared__ __bf16 Ah[128 * 128];   // 32 KB
    __shared__ __bf16 Al[128 * 128];   // 32 KB
    __shared__ __bf16 Bh[128 * 32];    // 8 KB
    __shared__ __bf16 Bl[128 * 32];    // 8 KB

    const int t = threadIdx.x;
    const int lane = t & 63;
    const int wid = t >> 6;           // 0..7
    const int wrow = wid & 3;         // 32-row quarter
    const int wcol = wid >> 2;        // 64-col half
    const int row0 = blockIdx.x * 128;
    const int g = t >> 3;             // 64 gather groups
    const int gl = t & 7;             // lane in group: k-cols gl*4 + 32*j

    f32x16 acc[2];
    #pragma unroll
    for (int nt = 0; nt < 2; ++nt)
        #pragma unroll
        for (int i = 0; i < 16; ++i) acc[nt][i] = 0.0f;

    for (int r = 0; r < 3; ++r) {
        const int* rp = rowptr + (size_t)r * RPS;
        const int2* eg = eint + (size_t)r * E_EDGES;
        const float* nd_ = ndv + (size_t)r * N_NODES;

        // ---- gather: each 8-lane group accumulates 2 rows, 4-edge unroll ----
        #pragma unroll
        for (int rr = 0; rr < 2; ++rr) {
            int rowl = g * 2 + rr;
            int grow = row0 + rowl;
            float4 a0 = {0,0,0,0}, a1 = {0,0,0,0}, a2 = {0,0,0,0}, a3 = {0,0,0,0};
            if (grow < N_NODES) {
                int beg = rp[grow], end = rp[grow + 1];
                float sc = nd_[grow];
                int e = beg;
                for (; e + 4 <= end; e += 4) {
                    int2 q0 = eg[e], q1 = eg[e + 1], q2 = eg[e + 2], q3 = eg[e + 3];
                    const float* p0 = h + (size_t)q0.x * D + gl * 4;
                    const float* p1 = h + (size_t)q1.x * D + gl * 4;
                    const float* p2 = h + (size_t)q2.x * D + gl * 4;
                    const float* p3 = h + (size_t)q3.x * D + gl * 4;
                    float4 u00 = *(const float4*)(p0),      u01 = *(const float4*)(p0 + 32);
                    float4 u02 = *(const float4*)(p0 + 64), u03 = *(const float4*)(p0 + 96);
                    float4 u10 = *(const float4*)(p1),      u11 = *(const float4*)(p1 + 32);
                    float4 u12 = *(const float4*)(p1 + 64), u13 = *(const float4*)(p1 + 96);
                    float4 u20 = *(const float4*)(p2),      u21 = *(const float4*)(p2 + 32);
                    float4 u22 = *(const float4*)(p2 + 64), u23 = *(const float4*)(p2 + 96);
                    float4 u30 = *(const float4*)(p3),      u31 = *(const float4*)(p3 + 32);
                    float4 u32 = *(const float4*)(p3 + 64), u33 = *(const float4*)(p3 + 96);
                    float wa = __int_as_float(q0.y), wb = __int_as_float(q1.y);
                    float wc = __int_as_float(q2.y), wd = __int_as_float(q3.y);
                    FMA16(wa, u00, u01, u02, u03);
                    FMA16(wb, u10, u11, u12, u13);
                    FMA16(wc, u20, u21, u22, u23);
                    FMA16(wd, u30, u31, u32, u33);
                }
                if (e + 2 <= end) {
                    int2 q0 = eg[e], q1 = eg[e + 1];
                    const float* p0 = h + (size_t)q0.x * D + gl * 4;
                    const float* p1 = h + (size_t)q1.x * D + gl * 4;
                    float4 u00 = *(const float4*)(p0),      u01 = *(const float4*)(p0 + 32);
                    float4 u02 = *(const float4*)(p0 + 64), u03 = *(const float4*)(p0 + 96);
                    float4 u10 = *(const float4*)(p1),      u11 = *(const float4*)(p1 + 32);
                    float4 u12 = *(const float4*)(p1 + 64), u13 = *(const float4*)(p1 + 96);
                    float wa = __int_as_float(q0.y), wb = __int_as_float(q1.y);
                    FMA16(wa, u00, u01, u02, u03);
                    FMA16(wb, u10, u11, u12, u13);
                    e += 2;
                }
                if (e < end) {
                    int2 q0 = eg[e];
                    const float* p0 = h + (size_t)q0.x * D + gl * 4;
                    float4 u00 = *(const float4*)(p0),      u01 = *(const float4*)(p0 + 32);
                    float4 u02 = *(const float4*)(p0 + 64), u03 = *(const float4*)(p0 + 96);
                    float wa = __int_as_float(q0.y);
                    FMA16(wa, u00, u01, u02, u03);
                }
                a0.x *= sc; a0.y *= sc; a0.z *= sc; a0.w *= sc;
                a1.x *= sc; a1.y *= sc; a1.z *= sc; a1.w *= sc;
                a2.x *= sc; a2.y *= sc; a2.z *= sc; a2.w *= sc;
                a3.x *= sc; a3.y *= sc; a3.z *= sc; a3.w *= sc;
            }
            float4 av[4] = {a0, a1, a2, a3};
            #pragma unroll
            for (int j = 0; j < 4; ++j) {
                int q = (gl >> 1) + 4 * j;
                int idx = rowl * 128 + qswz(rowl, q) * 8 + (gl & 1) * 4;
                bf16x4 hv, lv;
                float* ap = &av[j].x;
                #pragma unroll
                for (int c = 0; c < 4; ++c) {
                    __bf16 hb = (__bf16)ap[c];
                    hv[c] = hb;
                    lv[c] = (__bf16)(ap[c] - (float)hb);
                }
                *(bf16x4*)&Ah[idx] = hv;
                *(bf16x4*)&Al[idx] = lv;
            }
        }

        // ---- MFMA over 4 K-slices ----
        for (int ks = 0; ks < 4; ++ks) {
            // stage B slice: 128 cols x 32 k (hi+lo per thread)
            {
                int colj = t >> 2;
                int c = t & 3;
                int idx = colj * 32 + swz(colj, c) * 8;
                const __bf16* sh = Whi + (size_t)r * D * D + (size_t)colj * D + ks * 32 + c * 8;
                const __bf16* sl = Wlo + (size_t)r * D * D + (size_t)colj * D + ks * 32 + c * 8;
                *(bf16x8*)&Bh[idx] = *(const bf16x8*)sh;
                *(bf16x8*)&Bl[idx] = *(const bf16x8*)sl;
            }
            __syncthreads();   // A-writes (ks==0) and B-writes visible

            const int arow = lane & 31;
            const int kgrp = lane >> 5;
            #pragma unroll
            for (int ksub = 0; ksub < 2; ++ksub) {
                int ac = ksub * 2 + kgrp;
                int arow_g = wrow * 32 + arow;
                int aidx = arow_g * 128 + qswz(arow_g, ks * 4 + ac) * 8;
                bf16x8 ahv = *(const bf16x8*)&Ah[aidx];
                bf16x8 alv = *(const bf16x8*)&Al[aidx];
                #pragma unroll
                for (int nt = 0; nt < 2; ++nt) {
                    int colg = wcol * 64 + nt * 32 + arow;
                    int bidx = colg * 32 + swz(colg, ac) * 8;
                    bf16x8 bhv = *(const bf16x8*)&Bh[bidx];
                    bf16x8 blv = *(const bf16x8*)&Bl[bidx];
                    acc[nt] = __builtin_amdgcn_mfma_f32_32x32x16_bf16(ahv, bhv, acc[nt], 0, 0, 0);
                    acc[nt] = __builtin_amdgcn_mfma_f32_32x32x16_bf16(ahv, blv, acc[nt], 0, 0, 0);
                    acc[nt] = __builtin_amdgcn_mfma_f32_32x32x16_bf16(alv, bhv, acc[nt], 0, 0, 0);
                }
            }
            __syncthreads();   // MFMA reads done before next stage/gather writes
        }
    }

    // ---- epilogue: bias (+ ReLU), single write ----
    const int colb = lane & 31;
    const int rq = lane >> 5;
    #pragma unroll
    for (int nt = 0; nt < 2; ++nt) {
        int colg = wcol * 64 + nt * 32 + colb;
        float bv = bias[colg];
        #pragma unroll
        for (int reg = 0; reg < 16; ++reg) {
            int rowl = wrow * 32 + (reg & 3) + 8 * (reg >> 2) + 4 * rq;
            int grow = row0 + rowl;
            if (grow < N_NODES) {
                float z = acc[nt][reg] + bv;
                if (relu) z = fmaxf(z, 0.f);
                out[(size_t)grow * D + colg] = z;
            }
        }
    }
}

// ---------------- launch ----------------
extern "C" void kernel_launch(void* const* d_in, const int* in_sizes, int n_in,
                              void* d_out, int out_size, void* d_ws, size_t ws_size,
                              hipStream_t stream)
{
    const float* x      = (const float*)d_in[0];
    const int* seq_src  = (const int*)d_in[1];
    const int* seq_dst  = (const int*)d_in[2];
    const int* knn_src  = (const int*)d_in[3];
    const int* knn_dst  = (const int*)d_in[4];
    const int* dis_src  = (const int*)d_in[5];
    const int* dis_dst  = (const int*)d_in[6];
    const float* Wrel   = (const float*)d_in[7];   // [3][3][128][128]
    const float* brel   = (const float*)d_in[8];   // [3][3][128]
    const float* Wfc    = (const float*)d_in[9];   // [3][128][128]
    const float* bfc    = (const float*)d_in[10];  // [3][128]
    const float* gma    = (const float*)d_in[11];  // [2][128]
    const float* bta    = (const float*)d_in[12];
    const float* rmean  = (const float*)d_in[13];
    const float* rvar   = (const float*)d_in[14];
    float* out = (float*)d_out;

    const size_t ND = (size_t)N_NODES * D;
    float* ws   = (float*)d_ws;
    float* h0   = ws;                         // N*D
    float* h1   = h0 + ND;                    // N*D
    float* ns_  = h1 + ND;                    // 3*N
    float* nd_  = ns_ + 3 * N_NODES;          // 3*N
    float* bvec = nd_ + 3 * N_NODES;          // 3*128
    __bf16* Whi = (__bf16*)(bvec + 3 * D);    // 9*128*128
    __bf16* Wlo = Whi + (size_t)9 * D * D;
    int* outdeg = (int*)(Wlo + (size_t)9 * D * D);   // 3*N
    int* indeg  = outdeg + 3 * N_NODES;               // 3*N
    int* rowptr = indeg + 3 * N_NODES;                // 3*RPS
    int* cursor = rowptr + 3 * RPS;                   // 3*N
    int* bsum   = cursor + 3 * N_NODES;               // 3*SCAN_BLOCKS
    int2* eint  = (int2*)(bsum + 3 * SCAN_BLOCKS + 2); // 3*E {src, w} (8B aligned)

    // ---- graph preprocessing ----
    hipMemsetAsync(outdeg, 0, (size_t)6 * N_NODES * sizeof(int), stream);
    hist_kernel<<<dim3((E_EDGES / 4 + 255) / 256, 3), 256, 0, stream>>>(
        seq_src, seq_dst, knn_src, knn_dst, dis_src, dis_dst, outdeg, indeg);
    norm_kernel<<<dim3((N_NODES + 255) / 256, 3), 256, 0, stream>>>(outdeg, indeg, ns_, nd_);
    scan_part_kernel<<<dim3(SCAN_BLOCKS, 3), 256, 0, stream>>>(indeg, rowptr, bsum);
    scan_mid_kernel<<<1, 256, 0, stream>>>(bsum, rowptr);
    scan_add_kernel<<<dim3(SCAN_BLOCKS, 3), 256, 0, stream>>>(rowptr, bsum, cursor);
    fill_kernel<<<dim3((E_EDGES + 255) / 256, 3), 256, 0, stream>>>(
        seq_src, seq_dst, knn_src, knn_dst, dis_src, dis_dst, ns_, cursor, eint);

    // ---- weight/bias precompute ----
    wprep_kernel<<<dim3(9, 8), 256, 0, stream>>>(Wrel, Wfc, gma, rvar, Whi, Wlo);
    bias_prep_kernel<<<3, 128, 0, stream>>>(brel, Wfc, bfc, gma, bta, rmean, rvar, bvec);

    // ---- layers (fully fused) ----
    const int GB = (N_NODES + 127) / 128;   // 782
    fused_layer_kernel<<<GB, 512, 0, stream>>>(
        x, rowptr, eint, nd_, Whi, Wlo, h0, bvec, 1);
    fused_layer_kernel<<<GB, 512, 0, stream>>>(
        h0, rowptr, eint, nd_, Whi + (size_t)3 * D * D, Wlo + (size_t)3 * D * D,
        h1, bvec + D, 1);
    fused_layer_kernel<<<GB, 512, 0, stream>>>(
        h1, rowptr, eint, nd_, Whi + (size_t)6 * D * D, Wlo + (size_t)6 * D * D,
        out, bvec + 2 * D, 0);
}

// Round 10
// 782.951 us; speedup vs baseline: 1.4087x; 1.0111x over previous
//
#include <hip/hip_runtime.h>
#include <math.h>

#define N_NODES 100000
#define D 128
#define E_EDGES 600000
#define BN_EPS 1e-5f
#define RPS (N_NODES + 4)                 // padded rowptr stride per relation
#define N4V (N_NODES / 4)                 // 25000 int4 elements
#define SCAN_BLOCKS ((N4V + 255) / 256)   // 98

typedef __attribute__((ext_vector_type(8))) __bf16 bf16x8;
typedef __attribute__((ext_vector_type(4))) __bf16 bf16x4;
typedef __attribute__((ext_vector_type(16))) float f32x16;

// A-tile swizzle: full 4-bit XOR (best measured: 3.6M conflicts at BM=128)
__device__ __forceinline__ int qswz(int row, int q) { return q ^ (row & 15); }
// B-tile chunk swizzle
__device__ __forceinline__ int swz(int row, int c) { return c ^ ((row >> 1) & 3); }

// ---------------- degree histogram (all 3 relations, 4 edges/thread) ----------------
__global__ __launch_bounds__(256) void hist_kernel(
    const int* __restrict__ s0, const int* __restrict__ d0,
    const int* __restrict__ s1, const int* __restrict__ d1,
    const int* __restrict__ s2, const int* __restrict__ d2,
    int* __restrict__ outdeg, int* __restrict__ indeg)
{
    const int r = blockIdx.y;
    const int* src = (r == 0) ? s0 : ((r == 1) ? s1 : s2);
    const int* dst = (r == 0) ? d0 : ((r == 1) ? d1 : d2);
    int* od = outdeg + (size_t)r * N_NODES;
    int* id = indeg + (size_t)r * N_NODES;
    int i4 = blockIdx.x * 256 + threadIdx.x;
    if (i4 < E_EDGES / 4) {
        int4 s = ((const int4*)src)[i4];
        int4 d = ((const int4*)dst)[i4];
        atomicAdd(&od[s.x], 1); atomicAdd(&od[s.y], 1);
        atomicAdd(&od[s.z], 1); atomicAdd(&od[s.w], 1);
        atomicAdd(&id[d.x], 1); atomicAdd(&id[d.y], 1);
        atomicAdd(&id[d.z], 1); atomicAdd(&id[d.w], 1);
    }
}

// ---------------- norms ----------------
__global__ __launch_bounds__(256) void norm_kernel(
    const int* __restrict__ outdeg, const int* __restrict__ indeg,
    float* __restrict__ ns, float* __restrict__ nd)
{
    int n = blockIdx.x * 256 + threadIdx.x;
    int r = blockIdx.y;
    if (n < N_NODES) {
        int od = outdeg[r * N_NODES + n];
        int id = indeg[r * N_NODES + n];
        ns[r * N_NODES + n] = rsqrtf((float)(od < 1 ? 1 : od));
        nd[r * N_NODES + n] = rsqrtf((float)(id < 1 ? 1 : id));
    }
}

// ---------------- parallel scan pass 1: per-block local exclusive scan ----------------
__global__ __launch_bounds__(256) void scan_part_kernel(
    const int* __restrict__ indeg, int* __restrict__ rowptr, int* __restrict__ bsum)
{
    const int r = blockIdx.y;
    const int t = threadIdx.x;
    const int lane = t & 63, wid = t >> 6;
    __shared__ int wsum[4], woff[4];
    int i4 = blockIdx.x * 256 + t;
    int4 v = (i4 < N4V) ? ((const int4*)(indeg + (size_t)r * N_NODES))[i4]
                        : make_int4(0, 0, 0, 0);
    int s0 = v.x, s1 = s0 + v.y, s2 = s1 + v.z, s3 = s2 + v.w;
    int x = s3;
    #pragma unroll
    for (int off = 1; off < 64; off <<= 1) {
        int y = __shfl_up(x, off);
        if (lane >= off) x += y;
    }
    if (lane == 63) wsum[wid] = x;
    __syncthreads();
    if (t < 4) { int s = 0; for (int j = 0; j < t; ++j) s += wsum[j]; woff[t] = s; }
    __syncthreads();
    int base = woff[wid] + (x - s3);
    if (i4 < N4V) {
        int idx = i4 * 4;
        int* rp = rowptr + (size_t)r * RPS;
        rp[idx] = base; rp[idx + 1] = base + s0; rp[idx + 2] = base + s1; rp[idx + 3] = base + s2;
    }
    if (t == 255) bsum[r * SCAN_BLOCKS + blockIdx.x] = woff[3] + wsum[3];
}

// ---------------- scan pass 2 ----------------
__global__ __launch_bounds__(256) void scan_mid_kernel(
    int* __restrict__ bsum, int* __restrict__ rowptr)
{
    const int t = threadIdx.x;
    const int lane = t & 63, wid = t >> 6;
    if (wid >= 3) return;
    const int r = wid;
    int carry = 0;
    for (int c = 0; c < (SCAN_BLOCKS + 63) / 64; ++c) {
        int idx = c * 64 + lane;
        int v = (idx < SCAN_BLOCKS) ? bsum[r * SCAN_BLOCKS + idx] : 0;
        int x = v;
        #pragma unroll
        for (int off = 1; off < 64; off <<= 1) {
            int y = __shfl_up(x, off);
            if (lane >= off) x += y;
        }
        if (idx < SCAN_BLOCKS) bsum[r * SCAN_BLOCKS + idx] = carry + x - v;
        carry += __shfl(x, 63);
    }
    if (lane == 0) rowptr[(size_t)r * RPS + N_NODES] = carry;
}

// ---------------- scan pass 3: add block offsets, emit cursor copy ----------------
__global__ __launch_bounds__(256) void scan_add_kernel(
    int* __restrict__ rowptr, const int* __restrict__ bsum, int* __restrict__ cursor)
{
    const int r = blockIdx.y;
    int i4 = blockIdx.x * 256 + threadIdx.x;
    if (i4 < N4V) {
        int off = bsum[r * SCAN_BLOCKS + blockIdx.x];
        int4* rp4 = (int4*)(rowptr + (size_t)r * RPS);
        int4 v = rp4[i4];
        v.x += off; v.y += off; v.z += off; v.w += off;
        rp4[i4] = v;
        ((int4*)(cursor + (size_t)r * N_NODES))[i4] = v;
    }
}

// ---------------- CSR fill: edge record {src, ns[src]} ----------------
__global__ __launch_bounds__(256) void fill_kernel(
    const int* __restrict__ s0, const int* __restrict__ d0,
    const int* __restrict__ s1, const int* __restrict__ d1,
    const int* __restrict__ s2, const int* __restrict__ d2,
    const float* __restrict__ nsv,
    int* __restrict__ cursor, int2* __restrict__ eint)
{
    const int r = blockIdx.y;
    const int* src = (r == 0) ? s0 : ((r == 1) ? s1 : s2);
    const int* dst = (r == 0) ? d0 : ((r == 1) ? d1 : d2);
    int* cur = cursor + (size_t)r * N_NODES;
    int2* eg = eint + (size_t)r * E_EDGES;
    const float* ns_ = nsv + (size_t)r * N_NODES;
    int i = blockIdx.x * 256 + threadIdx.x;
    if (i < E_EDGES) {
        int s = src[i];
        int d = dst[i];
        int pos = atomicAdd(&cur[d], 1);
        eg[pos] = make_int2(s, __float_as_int(ns_[s]));
    }
}

// ---------------- W' precompute: grid (9, 8); block computes 16 k-rows x 128 cols ----------------
__global__ __launch_bounds__(256) void wprep_kernel(
    const float* __restrict__ Wrel, const float* __restrict__ Wfc,
    const float* __restrict__ gma, const float* __restrict__ rvar,
    __bf16* __restrict__ Whi, __bf16* __restrict__ Wlo)
{
    __shared__ float W2[128][132];
    __shared__ float W1p[16][132];
    const int b = blockIdx.x;   // l*3+r
    const int l = b / 3;
    const int by = blockIdx.y;  // k-row chunk
    const int t = threadIdx.x;

    const float* src1 = Wrel + (size_t)b * D * D;   // [k][j]
    const float* src2 = Wfc + (size_t)l * D * D;
    #pragma unroll
    for (int p = 0; p < 16; ++p) {
        int u = t + p * 256;
        int r = u >> 5, f = u & 31;
        *(float4*)&W2[r][f * 4] = *(const float4*)(src2 + r * D + f * 4);
    }
    #pragma unroll
    for (int p = 0; p < 2; ++p) {
        int u = t + p * 256;
        int r = u >> 5, f = u & 31;
        *(float4*)&W1p[r][f * 4] = *(const float4*)(src1 + (size_t)(by * 16 + r) * D + f * 4);
    }
    __syncthreads();

    const int rl = t >> 4;          // 0..15 local k-row
    const int cb = (t & 15) * 8;    // 8 cols
    float acc[8];
    #pragma unroll
    for (int j = 0; j < 8; ++j) acc[j] = 0.f;
    for (int k = 0; k < 128; ++k) {
        float a = W1p[rl][k];
        #pragma unroll
        for (int j = 0; j < 8; ++j) acc[j] = fmaf(a, W2[k][cb + j], acc[j]);
    }
    const int row = by * 16 + rl;
    #pragma unroll
    for (int j = 0; j < 8; ++j) {
        int colj = cb + j;
        float s = 1.0f;
        if (l < 2) s = gma[l * D + colj] * rsqrtf(rvar[l * D + colj] + BN_EPS);
        float v = acc[j] * s;
        __bf16 hb = (__bf16)v;
        __bf16 lb = (__bf16)(v - (float)hb);
        Whi[((size_t)b * D + colj) * D + row] = hb;
        Wlo[((size_t)b * D + colj) * D + row] = lb;
    }
}

// ---------------- bias precompute ----------------
__global__ __launch_bounds__(128) void bias_prep_kernel(
    const float* __restrict__ brel, const float* __restrict__ Wfc,
    const float* __restrict__ bfc,
    const float* __restrict__ gma, const float* __restrict__ bta,
    const float* __restrict__ rmean, const float* __restrict__ rvar,
    float* __restrict__ bvec)
{
    int j = threadIdx.x;
    int l = blockIdx.x;
    float acc = bfc[l * D + j];
    for (int k = 0; k < D; ++k) {
        float bs = brel[(l * 3 + 0) * D + k] + brel[(l * 3 + 1) * D + k] + brel[(l * 3 + 2) * D + k];
        acc = fmaf(bs, Wfc[((size_t)l * D + k) * D + j], acc);
    }
    if (l < 2) {
        float s = gma[l * D + j] * rsqrtf(rvar[l * D + j] + BN_EPS);
        acc = acc * s + (bta[l * D + j] - rmean[l * D + j] * s);
    }
    bvec[l * D + j] = acc;
}

// 16 FMAs of one edge's 4 float4 into the row accumulators a0..a3
#define FMA16(W_, P_, Q_, R_, S_)                                              \
    a0.x = fmaf(W_, P_.x, a0.x); a0.y = fmaf(W_, P_.y, a0.y);                  \
    a0.z = fmaf(W_, P_.z, a0.z); a0.w = fmaf(W_, P_.w, a0.w);                  \
    a1.x = fmaf(W_, Q_.x, a1.x); a1.y = fmaf(W_, Q_.y, a1.y);                  \
    a1.z = fmaf(W_, Q_.z, a1.z); a1.w = fmaf(W_, Q_.w, a1.w);                  \
    a2.x = fmaf(W_, R_.x, a2.x); a2.y = fmaf(W_, R_.y, a2.y);                  \
    a2.z = fmaf(W_, R_.z, a2.z); a2.w = fmaf(W_, R_.w, a2.w);                  \
    a3.x = fmaf(W_, S_.x, a3.x); a3.y = fmaf(W_, S_.y, a3.y);                  \
    a3.z = fmaf(W_, S_.z, a3.z); a3.w = fmaf(W_, S_.w, a3.w);

// ---------------- fused layer: gather -> bf16 hi/lo LDS -> MFMA vs W' (3 relations) ----------------
// BM=128 rows/block, 512 threads = 8 waves; wave w: rows (w&3)*32..+31, cols (w>>2)*64..+63.
// LDS 80 KB -> 2 blocks/CU. Gather: 8-lane groups, 2 rows each, 4-edge unroll
// (4 float4/lane/edge -> 16 loads in flight; launch_bounds(512,4) = 128 VGPR budget).
__global__ __launch_bounds__(512, 4) void fused_layer_kernel(
    const float* __restrict__ h,
    const int* __restrict__ rowptr,   // [3][RPS]
    const int2* __restrict__ eint,    // [3][E] {src, ns[src]}
    const float* __restrict__ ndv,    // [3][N]
    const __bf16* __restrict__ Whi,   // [3][col][k], this layer
    const __bf16* __restrict__ Wlo,
    float* __restrict__ out, const float* __restrict__ bias, int relu)
{
    __shared__ __bf16 Ah[128 * 128];   // 32 KB
    __shared__ __bf16 Al[128 * 128];   // 32 KB
    __shared__ __bf16 Bh[128 * 32];    // 8 KB
    __shared__ __bf16 Bl[128 * 32];    // 8 KB

    const int t = threadIdx.x;
    const int lane = t & 63;
    const int wid = t >> 6;           // 0..7
    const int wrow = wid & 3;         // 32-row quarter
    const int wcol = wid >> 2;        // 64-col half
    const int row0 = blockIdx.x * 128;
    const int g = t >> 3;             // 64 gather groups
    const int gl = t & 7;             // lane in group: k-cols gl*4 + 32*j

    f32x16 acc[2];
    #pragma unroll
    for (int nt = 0; nt < 2; ++nt)
        #pragma unroll
        for (int i = 0; i < 16; ++i) acc[nt][i] = 0.0f;

    for (int r = 0; r < 3; ++r) {
        const int* rp = rowptr + (size_t)r * RPS;
        const int2* eg = eint + (size_t)r * E_EDGES;
        const float* nd_ = ndv + (size_t)r * N_NODES;

        // ---- gather: each 8-lane group accumulates 2 rows, 4-edge unroll ----
        #pragma unroll
        for (int rr = 0; rr < 2; ++rr) {
            int rowl = g * 2 + rr;
            int grow = row0 + rowl;
            float4 a0 = {0,0,0,0}, a1 = {0,0,0,0}, a2 = {0,0,0,0}, a3 = {0,0,0,0};
            if (grow < N_NODES) {
                int beg = rp[grow], end = rp[grow + 1];
                float sc = nd_[grow];
                int e = beg;
                for (; e + 4 <= end; e += 4) {
                    int2 q0 = eg[e], q1 = eg[e + 1], q2 = eg[e + 2], q3 = eg[e + 3];
                    const float* p0 = h + (size_t)q0.x * D + gl * 4;
                    const float* p1 = h + (size_t)q1.x * D + gl * 4;
                    const float* p2 = h + (size_t)q2.x * D + gl * 4;
                    const float* p3 = h + (size_t)q3.x * D + gl * 4;
                    float4 u00 = *(const float4*)(p0),      u01 = *(const float4*)(p0 + 32);
                    float4 u02 = *(const float4*)(p0 + 64), u03 = *(const float4*)(p0 + 96);
                    float4 u10 = *(const float4*)(p1),      u11 = *(const float4*)(p1 + 32);
                    float4 u12 = *(const float4*)(p1 + 64), u13 = *(const float4*)(p1 + 96);
                    float4 u20 = *(const float4*)(p2),      u21 = *(const float4*)(p2 + 32);
                    float4 u22 = *(const float4*)(p2 + 64), u23 = *(const float4*)(p2 + 96);
                    float4 u30 = *(const float4*)(p3),      u31 = *(const float4*)(p3 + 32);
                    float4 u32 = *(const float4*)(p3 + 64), u33 = *(const float4*)(p3 + 96);
                    float wa = __int_as_float(q0.y), wb = __int_as_float(q1.y);
                    float wc = __int_as_float(q2.y), wd = __int_as_float(q3.y);
                    FMA16(wa, u00, u01, u02, u03);
                    FMA16(wb, u10, u11, u12, u13);
                    FMA16(wc, u20, u21, u22, u23);
                    FMA16(wd, u30, u31, u32, u33);
                }
                if (e + 2 <= end) {
                    int2 q0 = eg[e], q1 = eg[e + 1];
                    const float* p0 = h + (size_t)q0.x * D + gl * 4;
                    const float* p1 = h + (size_t)q1.x * D + gl * 4;
                    float4 u00 = *(const float4*)(p0),      u01 = *(const float4*)(p0 + 32);
                    float4 u02 = *(const float4*)(p0 + 64), u03 = *(const float4*)(p0 + 96);
                    float4 u10 = *(const float4*)(p1),      u11 = *(const float4*)(p1 + 32);
                    float4 u12 = *(const float4*)(p1 + 64), u13 = *(const float4*)(p1 + 96);
                    float wa = __int_as_float(q0.y), wb = __int_as_float(q1.y);
                    FMA16(wa, u00, u01, u02, u03);
                    FMA16(wb, u10, u11, u12, u13);
                    e += 2;
                }
                if (e < end) {
                    int2 q0 = eg[e];
                    const float* p0 = h + (size_t)q0.x * D + gl * 4;
                    float4 u00 = *(const float4*)(p0),      u01 = *(const float4*)(p0 + 32);
                    float4 u02 = *(const float4*)(p0 + 64), u03 = *(const float4*)(p0 + 96);
                    float wa = __int_as_float(q0.y);
                    FMA16(wa, u00, u01, u02, u03);
                }
                a0.x *= sc; a0.y *= sc; a0.z *= sc; a0.w *= sc;
                a1.x *= sc; a1.y *= sc; a1.z *= sc; a1.w *= sc;
                a2.x *= sc; a2.y *= sc; a2.z *= sc; a2.w *= sc;
                a3.x *= sc; a3.y *= sc; a3.z *= sc; a3.w *= sc;
            }
            float4 av[4] = {a0, a1, a2, a3};
            #pragma unroll
            for (int j = 0; j < 4; ++j) {
                int q = (gl >> 1) + 4 * j;
                int idx = rowl * 128 + qswz(rowl, q) * 8 + (gl & 1) * 4;
                bf16x4 hv, lv;
                float* ap = &av[j].x;
                #pragma unroll
                for (int c = 0; c < 4; ++c) {
                    __bf16 hb = (__bf16)ap[c];
                    hv[c] = hb;
                    lv[c] = (__bf16)(ap[c] - (float)hb);
                }
                *(bf16x4*)&Ah[idx] = hv;
                *(bf16x4*)&Al[idx] = lv;
            }
        }

        // ---- MFMA over 4 K-slices ----
        for (int ks = 0; ks < 4; ++ks) {
            // stage B slice: 128 cols x 32 k (hi+lo per thread)
            {
                int colj = t >> 2;
                int c = t & 3;
                int idx = colj * 32 + swz(colj, c) * 8;
                const __bf16* sh = Whi + (size_t)r * D * D + (size_t)colj * D + ks * 32 + c * 8;
                const __bf16* sl = Wlo + (size_t)r * D * D + (size_t)colj * D + ks * 32 + c * 8;
                *(bf16x8*)&Bh[idx] = *(const bf16x8*)sh;
                *(bf16x8*)&Bl[idx] = *(const bf16x8*)sl;
            }
            __syncthreads();   // A-writes (ks==0) and B-writes visible

            const int arow = lane & 31;
            const int kgrp = lane >> 5;
            #pragma unroll
            for (int ksub = 0; ksub < 2; ++ksub) {
                int ac = ksub * 2 + kgrp;
                int arow_g = wrow * 32 + arow;
                int aidx = arow_g * 128 + qswz(arow_g, ks * 4 + ac) * 8;
                bf16x8 ahv = *(const bf16x8*)&Ah[aidx];
                bf16x8 alv = *(const bf16x8*)&Al[aidx];
                #pragma unroll
                for (int nt = 0; nt < 2; ++nt) {
                    int colg = wcol * 64 + nt * 32 + arow;
                    int bidx = colg * 32 + swz(colg, ac) * 8;
                    bf16x8 bhv = *(const bf16x8*)&Bh[bidx];
                    bf16x8 blv = *(const bf16x8*)&Bl[bidx];
                    acc[nt] = __builtin_amdgcn_mfma_f32_32x32x16_bf16(ahv, bhv, acc[nt], 0, 0, 0);
                    acc[nt] = __builtin_amdgcn_mfma_f32_32x32x16_bf16(ahv, blv, acc[nt], 0, 0, 0);
                    acc[nt] = __builtin_amdgcn_mfma_f32_32x32x16_bf16(alv, bhv, acc[nt], 0, 0, 0);
                }
            }
            __syncthreads();   // MFMA reads done before next stage/gather writes
        }
    }

    // ---- epilogue: bias (+ ReLU), single write ----
    const int colb = lane & 31;
    const int rq = lane >> 5;
    #pragma unroll
    for (int nt = 0; nt < 2; ++nt) {
        int colg = wcol * 64 + nt * 32 + colb;
        float bv = bias[colg];
        #pragma unroll
        for (int reg = 0; reg < 16; ++reg) {
            int rowl = wrow * 32 + (reg & 3) + 8 * (reg >> 2) + 4 * rq;
            int grow = row0 + rowl;
            if (grow < N_NODES) {
                float z = acc[nt][reg] + bv;
                if (relu) z = fmaxf(z, 0.f);
                out[(size_t)grow * D + colg] = z;
            }
        }
    }
}

// ---------------- launch ----------------
extern "C" void kernel_launch(void* const* d_in, const int* in_sizes, int n_in,
                              void* d_out, int out_size, void* d_ws, size_t ws_size,
                              hipStream_t stream)
{
    const float* x      = (const float*)d_in[0];
    const int* seq_src  = (const int*)d_in[1];
    const int* seq_dst  = (const int*)d_in[2];
    const int* knn_src  = (const int*)d_in[3];
    const int* knn_dst  = (const int*)d_in[4];
    const int* dis_src  = (const int*)d_in[5];
    const int* dis_dst  = (const int*)d_in[6];
    const float* Wrel   = (const float*)d_in[7];   // [3][3][128][128]
    const float* brel   = (const float*)d_in[8];   // [3][3][128]
    const float* Wfc    = (const float*)d_in[9];   // [3][128][128]
    const float* bfc    = (const float*)d_in[10];  // [3][128]
    const float* gma    = (const float*)d_in[11];  // [2][128]
    const float* bta    = (const float*)d_in[12];
    const float* rmean  = (const float*)d_in[13];
    const float* rvar   = (const float*)d_in[14];
    float* out = (float*)d_out;

    const size_t ND = (size_t)N_NODES * D;
    float* ws   = (float*)d_ws;
    float* h0   = ws;                         // N*D
    float* h1   = h0 + ND;                    // N*D
    float* ns_  = h1 + ND;                    // 3*N
    float* nd_  = ns_ + 3 * N_NODES;          // 3*N
    float* bvec = nd_ + 3 * N_NODES;          // 3*128
    __bf16* Whi = (__bf16*)(bvec + 3 * D);    // 9*128*128
    __bf16* Wlo = Whi + (size_t)9 * D * D;
    int* outdeg = (int*)(Wlo + (size_t)9 * D * D);   // 3*N
    int* indeg  = outdeg + 3 * N_NODES;               // 3*N
    int* rowptr = indeg + 3 * N_NODES;                // 3*RPS
    int* cursor = rowptr + 3 * RPS;                   // 3*N
    int* bsum   = cursor + 3 * N_NODES;               // 3*SCAN_BLOCKS
    int2* eint  = (int2*)(bsum + 3 * SCAN_BLOCKS + 2); // 3*E {src, w} (8B aligned)

    // ---- graph preprocessing ----
    hipMemsetAsync(outdeg, 0, (size_t)6 * N_NODES * sizeof(int), stream);
    hist_kernel<<<dim3((E_EDGES / 4 + 255) / 256, 3), 256, 0, stream>>>(
        seq_src, seq_dst, knn_src, knn_dst, dis_src, dis_dst, outdeg, indeg);
    norm_kernel<<<dim3((N_NODES + 255) / 256, 3), 256, 0, stream>>>(outdeg, indeg, ns_, nd_);
    scan_part_kernel<<<dim3(SCAN_BLOCKS, 3), 256, 0, stream>>>(indeg, rowptr, bsum);
    scan_mid_kernel<<<1, 256, 0, stream>>>(bsum, rowptr);
    scan_add_kernel<<<dim3(SCAN_BLOCKS, 3), 256, 0, stream>>>(rowptr, bsum, cursor);
    fill_kernel<<<dim3((E_EDGES + 255) / 256, 3), 256, 0, stream>>>(
        seq_src, seq_dst, knn_src, knn_dst, dis_src, dis_dst, ns_, cursor, eint);

    // ---- weight/bias precompute ----
    wprep_kernel<<<dim3(9, 8), 256, 0, stream>>>(Wrel, Wfc, gma, rvar, Whi, Wlo);
    bias_prep_kernel<<<3, 128, 0, stream>>>(brel, Wfc, bfc, gma, bta, rmean, rvar, bvec);

    // ---- layers (fully fused) ----
    const int GB = (N_NODES + 127) / 128;   // 782
    fused_layer_kernel<<<GB, 512, 0, stream>>>(
        x, rowptr, eint, nd_, Whi, Wlo, h0, bvec, 1);
    fused_layer_kernel<<<GB, 512, 0, stream>>>(
        h0, rowptr, eint, nd_, Whi + (size_t)3 * D * D, Wlo + (size_t)3 * D * D,
        h1, bvec + D, 1);
    fused_layer_kernel<<<GB, 512, 0, stream>>>(
        h1, rowptr, eint, nd_, Whi + (size_t)6 * D * D, Wlo + (size_t)6 * D * D,
        out, bvec + 2 * D, 0);
}